// Round 6
// baseline (5065541.797 us; speedup 1.0000x reference)
//
#include <hip/hip_runtime.h>

// LSTMClassification: B=64, T=512, IN=128, H=512, 2 layers + FC(512->1)
// Round 6: XCD-local exchange. Grid 512x256; residue 0 -> layer0 (64 WGs),
// residue 1 -> layer1, others exit. Under the measured round-robin block->XCD
// mapping each layer lands on ONE XCD (2 blocks/CU x 32 CU). A one-time
// HW_REG_XCC_ID verification enables the FAST path: own-layer h + flags via
// sc0-only ops (XCD L2, ~200cyc RT) instead of MALL bypass (~1.5-2us RT,
// the round-3..5 bottleneck). Placement NOT assumed for correctness: if a
// layer's WGs straddle XCDs it falls back to the proven sc0sc1 MALL path.
// Cross-layer h0_all + dep flags always MALL-grade; L0's mall publication is
// done by waves 2-3 with a one-step-deferred flag (vmcnt(1) attestation) so
// MALL store acks stay off layer0's recurrent critical chain.
// Round-5 RMW regression reverted: plain flag stores, dense flag arrays.

#define NWG 64
#define NB 64
#define NT 512
#define NH 512
#define BLK 512    // elements per WG h-block

typedef float f32x4 __attribute__((ext_vector_type(4)));
typedef __bf16 bf16x4 __attribute__((ext_vector_type(4)));
typedef __bf16 bf16x8 __attribute__((ext_vector_type(8)));
typedef unsigned long long u64;

__device__ __forceinline__ void waitv0() {
    asm volatile("s_waitcnt vmcnt(0)" ::: "memory");
    __builtin_amdgcn_sched_barrier(0);
}
__device__ __forceinline__ void waitv1() {
    asm volatile("s_waitcnt vmcnt(1)" ::: "memory");
    __builtin_amdgcn_sched_barrier(0);
}

template<bool FAST> __device__ __forceinline__ u64 ld8(const __bf16* p) {
    u64 v;
    if constexpr (FAST)
        asm volatile("global_load_dwordx2 %0, %1, off sc0" : "=v"(v) : "v"(p) : "memory");
    else
        asm volatile("global_load_dwordx2 %0, %1, off sc0 sc1" : "=v"(v) : "v"(p) : "memory");
    return v;   // caller must waitv0() before use
}
template<bool FAST> __device__ __forceinline__ void st8(__bf16* p, u64 v) {
    if constexpr (FAST)
        asm volatile("global_store_dwordx2 %0, %1, off sc0" :: "v"(p), "v"(v) : "memory");
    else
        asm volatile("global_store_dwordx2 %0, %1, off sc0 sc1" :: "v"(p), "v"(v) : "memory");
}
template<bool FAST> __device__ __forceinline__ unsigned ldf(const unsigned* p) {
    unsigned v;
    if constexpr (FAST)
        asm volatile("global_load_dword %0, %1, off sc0\n\ts_waitcnt vmcnt(0)"
                     : "=v"(v) : "v"(p) : "memory");
    else
        asm volatile("global_load_dword %0, %1, off sc0 sc1\n\ts_waitcnt vmcnt(0)"
                     : "=v"(v) : "v"(p) : "memory");
    __builtin_amdgcn_sched_barrier(0);
    return v;
}
template<bool FAST> __device__ __forceinline__ void stf(unsigned* p, unsigned v) {
    if constexpr (FAST)
        asm volatile("global_store_dword %0, %1, off sc0" :: "v"(p), "v"(v) : "memory");
    else
        asm volatile("global_store_dword %0, %1, off sc0 sc1" :: "v"(p), "v"(v) : "memory");
}

// wave0 (lanes 0..63): poll 64 dense flags until all >= tgt.
template<bool FAST>
__device__ __forceinline__ void pollge(const unsigned* f, unsigned tgt, int lane) {
    int g = 0;
    for (;;) {
        unsigned v = ldf<FAST>(f + lane);
        if (__all((int)(v >= tgt))) break;
        if (++g > (1 << 17)) break;    // safety: never hard-hang
    }
}

__device__ __forceinline__ unsigned short bfbits(float f) {
    __bf16 h = (__bf16)f; unsigned short u; __builtin_memcpy(&u, &h, 2); return u;
}

__global__ void prep_kernel(unsigned short* hs0, unsigned short* hs1, unsigned* fl) {
    int i = blockIdx.x * blockDim.x + threadIdx.x;
    if (i < 2 * NWG * BLK) { hs0[i] = 0; hs1[i] = 0; }   // both parity bufs, both layers
    if (i < 320) fl[i] = 0;                              // fl0[64] fl1[64] flm[64] xa[128]
}

template<int KIH, int IS_L0, bool FAST>
__device__ void layer_loop(
    char* Wl, float (*gbuf)[36], float (*c_lds)[8], unsigned (*hstage32)[4],
    int wg,
    const float* __restrict__ W_ih, const float* __restrict__ W_hh,
    const float* __restrict__ b_ih, const float* __restrict__ b_hh,
    const float* __restrict__ x_f32,        // L0 only
    const __bf16* __restrict__ h_in_all,    // L1: h0_all [NT][NWG][512] (MALL)
    __bf16* __restrict__ h_out_all,         // L0: h0_all (MALL)
    __bf16* __restrict__ hloc,              // [2][NWG][512] own-layer parity exchange
    float* __restrict__ h_final,            // L1 only
    unsigned* __restrict__ fl_loc,          // [64] own-layer step flags
    unsigned* __restrict__ fl_mall_self,    // [64] L0 writes (deferred)
    const unsigned* __restrict__ fl_mall_dep)
{
    constexpr int KTOT = KIH + NH;
    constexpr int NCH_A = KIH / 32;
    constexpr int NCH_B = NH / 32;          // 16
    constexpr int ROWB = KTOT * 2;

    const int tid = threadIdx.x, lane = tid & 63, wid = tid >> 6;
    const int hcol0 = wg * 8;

    // ---- stage weight slice into LDS (bf16, row-XOR swizzle) ----
    {
        constexpr int CPR = KTOT / 8;
        for (int cid = tid; cid < 32 * CPR; cid += 256) {
            const int r = cid / CPR;
            const int k0 = (cid - r * CPR) * 8;
            const int grow = (r >> 3) * NH + hcol0 + (r & 7);
            const float* src = (k0 < KIH) ? (W_ih + (size_t)grow * KIH + k0)
                                          : (W_hh + (size_t)grow * NH + (k0 - KIH));
            union { __bf16 h[8]; uint4 u; } tmp;
            #pragma unroll
            for (int j = 0; j < 8; ++j) tmp.h[j] = (__bf16)src[j];
            const unsigned off = (unsigned)(r * ROWB) +
                (((unsigned)(2 * k0)) ^ ((unsigned)((r & 7) << 4)));
            *(uint4*)(Wl + off) = tmp.u;
        }
    }

    // epilogue mapping: thread -> (batch eb, 2 cols ecp..ecp+1)
    const int eb = tid >> 2, ecp = (tid & 3) * 2;
    float bI[2], bF[2], bG[2], bO[2];
    #pragma unroll
    for (int j = 0; j < 2; ++j) {
        const int c = hcol0 + ecp + j;
        bI[j] = b_ih[c] + b_hh[c];
        bF[j] = b_ih[NH + c] + b_hh[NH + c];
        bG[j] = b_ih[2 * NH + c] + b_hh[2 * NH + c];
        bO[j] = b_ih[3 * NH + c] + b_hh[3 * NH + c];
    }
    c_lds[eb][ecp] = 0.f; c_lds[eb][ecp + 1] = 0.f;
    __syncthreads();

    // MFMA mapping: 4 waves = 4 batch-tiles; each wave does both gate-tiles
    const int bt = wid * 16;
    const int arow = bt + (lane & 15);
    const int q4 = ((lane >> 4) & 3) * 4;
    const char* wrow0 = Wl + (lane & 15) * ROWB;
    const char* wrow1 = wrow0 + 16 * ROWB;
    const unsigned bsz = (unsigned)((lane & 7) << 4);
    const int aoff = arow * 8 + (q4 & 4);
    const int bsub = (q4 >> 3);

    auto wfragp = [&](const char* wr, int k0) -> bf16x8 {
        const bf16x4 lo = *(const bf16x4*)(wr + (((unsigned)(2 * (k0 + q4))) ^ bsz));
        const bf16x4 hi = *(const bf16x4*)(wr + (((unsigned)(2 * (k0 + 16 + q4))) ^ bsz));
        return __builtin_shufflevector(lo, hi, 0, 1, 2, 3, 4, 5, 6, 7);
    };
    auto mk8 = [&](u64 a, u64 b) -> bf16x8 {
        bf16x4 lo, hi; __builtin_memcpy(&lo, &a, 8); __builtin_memcpy(&hi, &b, 8);
        return __builtin_shufflevector(lo, hi, 0, 1, 2, 3, 4, 5, 6, 7);
    };

    for (int t = 0; t < NT; ++t) {
        const __bf16* hprev = hloc + (size_t)(t & 1) * NWG * BLK;
        __bf16* hout = hloc + (size_t)((t + 1) & 1) * NWG * BLK;

        f32x4 a0c0 = {0,0,0,0}, a0c1 = {0,0,0,0};   // gate-tile 0 (2 chains)
        f32x4 a1c0 = {0,0,0,0}, a1c1 = {0,0,0,0};   // gate-tile 1

        if constexpr (IS_L0) {
            // phase A from x (cached; independent of recurrence) BEFORE the wait
            const float* xb = x_f32 + ((size_t)arow * NT + t) * KIH;
            #pragma unroll
            for (int kk = 0; kk < NCH_A; ++kk) {
                const float4 lo = *(const float4*)(xb + kk * 32 + q4);
                const float4 hi = *(const float4*)(xb + kk * 32 + 16 + q4);
                const bf16x4 alo = {(__bf16)lo.x, (__bf16)lo.y, (__bf16)lo.z, (__bf16)lo.w};
                const bf16x4 ahi = {(__bf16)hi.x, (__bf16)hi.y, (__bf16)hi.z, (__bf16)hi.w};
                const bf16x8 av = __builtin_shufflevector(alo, ahi, 0, 1, 2, 3, 4, 5, 6, 7);
                f32x4& d0 = (kk & 1) ? a0c1 : a0c0;
                d0 = __builtin_amdgcn_mfma_f32_16x16x32_bf16(av, wfragp(wrow0, kk * 32), d0, 0, 0, 0);
                f32x4& d1 = (kk & 1) ? a1c1 : a1c0;
                d1 = __builtin_amdgcn_mfma_f32_16x16x32_bf16(av, wfragp(wrow1, kk * 32), d1, 0, 0, 0);
            }
        }

        // waits (wave0 polls; barrier gates the loads)
        if (wid == 0) {
            if constexpr (!IS_L0) pollge<false>(fl_mall_dep, (unsigned)(t + 1), lane);
            if (t > 0) pollge<FAST>(fl_loc, (unsigned)t, lane);
        }
        __syncthreads();

        // recurrence loads (own layer, FAST grade)
        u64 rb[2 * NCH_B];
        #pragma unroll
        for (int kk = 0; kk < NCH_B; ++kk) {
            const __bf16* base = hprev + (4 * kk + bsub) * BLK + aoff;
            rb[2 * kk]     = ld8<FAST>(base);
            rb[2 * kk + 1] = ld8<FAST>(base + 2 * BLK);
        }
        if constexpr (!IS_L0) {
            // L1 phase-A input from h0_all (always MALL grade)
            u64 ra[2 * NCH_A];
            const __bf16* hA = h_in_all + (size_t)t * NWG * BLK;
            #pragma unroll
            for (int kk = 0; kk < NCH_A; ++kk) {
                const __bf16* base = hA + (4 * kk + bsub) * BLK + aoff;
                ra[2 * kk]     = ld8<false>(base);
                ra[2 * kk + 1] = ld8<false>(base + 2 * BLK);
            }
            waitv0();
            #pragma unroll
            for (int kk = 0; kk < NCH_A; ++kk) {
                const bf16x8 av = mk8(ra[2 * kk], ra[2 * kk + 1]);
                f32x4& d0 = (kk & 1) ? a0c1 : a0c0;
                d0 = __builtin_amdgcn_mfma_f32_16x16x32_bf16(av, wfragp(wrow0, kk * 32), d0, 0, 0, 0);
                f32x4& d1 = (kk & 1) ? a1c1 : a1c0;
                d1 = __builtin_amdgcn_mfma_f32_16x16x32_bf16(av, wfragp(wrow1, kk * 32), d1, 0, 0, 0);
            }
        } else {
            waitv0();
        }
        #pragma unroll
        for (int kk = 0; kk < NCH_B; ++kk) {
            const bf16x8 av = mk8(rb[2 * kk], rb[2 * kk + 1]);
            f32x4& d0 = (kk & 1) ? a0c1 : a0c0;
            d0 = __builtin_amdgcn_mfma_f32_16x16x32_bf16(av, wfragp(wrow0, KIH + kk * 32), d0, 0, 0, 0);
            f32x4& d1 = (kk & 1) ? a1c1 : a1c0;
            d1 = __builtin_amdgcn_mfma_f32_16x16x32_bf16(av, wfragp(wrow1, KIH + kk * 32), d1, 0, 0, 0);
        }

        const f32x4 s0 = a0c0 + a0c1, s1 = a1c0 + a1c1;
        #pragma unroll
        for (int i = 0; i < 4; ++i) {
            gbuf[bt + ((lane >> 4) & 3) * 4 + i][lane & 15]        = s0[i];
            gbuf[bt + ((lane >> 4) & 3) * 4 + i][16 + (lane & 15)] = s1[i];
        }
        __syncthreads();   // S1: gbuf ready; prev-step hstage readers done

        // LSTM cell, fp32, 2 columns per thread
        {
            float hh[2];
            #pragma unroll
            for (int j = 0; j < 2; ++j) {
                const int c = ecp + j;
                const float gi = gbuf[eb][c]      + bI[j];
                const float gf = gbuf[eb][8 + c]  + bF[j];
                const float gg = gbuf[eb][16 + c] + bG[j];
                const float go = gbuf[eb][24 + c] + bO[j];
                const float ii = 1.f / (1.f + __expf(-gi));
                const float ff = 1.f / (1.f + __expf(-gf));
                const float g2 = 2.f / (1.f + __expf(-2.f * gg)) - 1.f;
                const float oo = 1.f / (1.f + __expf(-go));
                const float cn = ff * c_lds[eb][c] + ii * g2;
                const float th = 2.f / (1.f + __expf(-2.f * cn)) - 1.f;
                const float hn = oo * th;
                c_lds[eb][c] = cn;
                hh[j] = hn;
            }
            hstage32[eb][tid & 3] = (unsigned)bfbits(hh[0]) | ((unsigned)bfbits(hh[1]) << 16);
            if constexpr (!IS_L0) {
                if (t == NT - 1) {
                    h_final[(size_t)eb * NH + hcol0 + ecp]     = hh[0];
                    h_final[(size_t)eb * NH + hcol0 + ecp + 1] = hh[1];
                }
            }
        }
        __syncthreads();   // S2: hstage ready

        if (tid < 128) {
            // local publish (waves 0-1): never touch MALL -> clean fast drain
            const u64 v = ((const u64*)hstage32)[tid];
            st8<FAST>(hout + (size_t)wg * BLK + tid * 4, v);
            waitv0();
        } else {
            if constexpr (IS_L0) waitv1();   // attest mall batch t-2 done (waves 2-3)
        }
        __syncthreads();   // S3: all drained / attested
        if (tid == 0) stf<FAST>(&fl_loc[wg], (unsigned)(t + 1));
        if constexpr (IS_L0) {
            if (tid == 128 && t >= 2) stf<false>(&fl_mall_self[wg], (unsigned)(t - 1));
            if (tid >= 128) {
                const u64 v = ((const u64*)hstage32)[tid - 128];
                st8<false>(h_out_all + ((size_t)t * NWG + wg) * BLK + (tid - 128) * 4, v);
            }
        }
    }

    if constexpr (IS_L0) {
        if (tid >= 128) waitv0();
        __syncthreads();
        if (tid == 128) stf<false>(&fl_mall_self[wg], (unsigned)NT);
    }
}

__launch_bounds__(256, 2)
__global__ void lstm_fused_kernel(
    const float* W_ih0, const float* W_hh0, const float* b_ih0, const float* b_hh0,
    const float* W_ih1, const float* W_hh1, const float* b_ih1, const float* b_hh1,
    const float* x, __bf16* h0_all, __bf16* hs0, __bf16* hs1, float* hfin,
    unsigned* fl0, unsigned* fl1, unsigned* flm, unsigned* xa)
{
    __shared__ __align__(16) char Wl[32 * 2048];
    __shared__ float gbuf[64][36];
    __shared__ float c_lds[64][8];
    __shared__ unsigned hstage32[64][4];
    __shared__ int fastsh;

    const int res = blockIdx.x & 7;
    const int wg = blockIdx.x >> 3;
    if (res > 1) return;                     // dead block
    const int layer = res;
    const int tid = threadIdx.x;

    // ---- one-time XCD co-residency verification (correctness-safe) ----
    unsigned xcc = 0;
    asm volatile("s_getreg_b32 %0, hwreg(HW_REG_XCC_ID)" : "=s"(xcc));
    if (tid == 0)
        __hip_atomic_store(&xa[layer * 64 + wg], xcc | 256u,
                           __ATOMIC_RELAXED, __HIP_MEMORY_SCOPE_AGENT);
    if (tid < 64) {
        unsigned v = 0; int g = 0;
        for (;;) {
            v = __hip_atomic_load(&xa[layer * 64 + tid],
                                  __ATOMIC_RELAXED, __HIP_MEMORY_SCOPE_AGENT);
            if (__all((int)(v >= 256u))) break;
            if (++g > (1 << 18)) break;
        }
        const unsigned v0 = __shfl(v, 0);
        const int ok = __all((int)(v == v0)) && (g <= (1 << 18));
        if (tid == 0) fastsh = ok;
    }
    __syncthreads();
    const bool fast = (fastsh != 0);

    if (layer == 0) {
        if (fast)
            layer_loop<128, 1, true >(Wl, gbuf, c_lds, hstage32, wg, W_ih0, W_hh0, b_ih0, b_hh0,
                                      x, nullptr, h0_all, hs0, nullptr, fl0, flm, nullptr);
        else
            layer_loop<128, 1, false>(Wl, gbuf, c_lds, hstage32, wg, W_ih0, W_hh0, b_ih0, b_hh0,
                                      x, nullptr, h0_all, hs0, nullptr, fl0, flm, nullptr);
    } else {
        if (fast)
            layer_loop<512, 0, true >(Wl, gbuf, c_lds, hstage32, wg, W_ih1, W_hh1, b_ih1, b_hh1,
                                      nullptr, h0_all, nullptr, hs1, hfin, fl1, nullptr, flm);
        else
            layer_loop<512, 0, false>(Wl, gbuf, c_lds, hstage32, wg, W_ih1, W_hh1, b_ih1, b_hh1,
                                      nullptr, h0_all, nullptr, hs1, hfin, fl1, nullptr, flm);
    }
}

__global__ void fc_kernel(const float* __restrict__ hfin,
                          const float* __restrict__ w_fc,
                          const float* __restrict__ b_fc,
                          float* __restrict__ out) {
    __shared__ float red[64][9];
    const int tid = threadIdx.x;
    const int b = tid >> 3, p = tid & 7;
    const int k0 = p * 64;
    float s = 0.f;
    #pragma unroll 8
    for (int k = 0; k < 64; ++k) s += hfin[(size_t)b * NH + k0 + k] * w_fc[k0 + k];
    red[b][p] = s;
    __syncthreads();
    if (p == 0) {
        float a = 0.f;
        #pragma unroll
        for (int j = 0; j < 8; ++j) a += red[b][j];
        out[b] = a + b_fc[0];
    }
}

extern "C" void kernel_launch(void* const* d_in, const int* in_sizes, int n_in,
                              void* d_out, int out_size, void* d_ws, size_t ws_size,
                              hipStream_t stream) {
    const float* x     = (const float*)d_in[0];
    const float* W_ih0 = (const float*)d_in[1];
    const float* W_hh0 = (const float*)d_in[2];
    const float* b_ih0 = (const float*)d_in[3];
    const float* b_hh0 = (const float*)d_in[4];
    const float* W_ih1 = (const float*)d_in[5];
    const float* W_hh1 = (const float*)d_in[6];
    const float* b_ih1 = (const float*)d_in[7];
    const float* b_hh1 = (const float*)d_in[8];
    const float* W_fc  = (const float*)d_in[9];
    const float* b_fc  = (const float*)d_in[10];

    // workspace layout (bytes); total ~33.95 MB
    char* ws = (char*)d_ws;
    __bf16*  h0_all = (__bf16*)(ws);                        // 512*64*512*2 = 33,554,432
    __bf16*  hs0    = (__bf16*)(ws + 33554432);             // 2*64*512*2 = 131,072
    __bf16*  hs1    = (__bf16*)(ws + 33554432 + 131072);    // 131,072
    float*   hfin   = (float*) (ws + 33554432 + 262144);    // 131,072
    unsigned* fl0   = (unsigned*)(ws + 33554432 + 393216);  // 64 u32
    unsigned* fl1   = fl0 + 64;                             // 64
    unsigned* flm   = fl0 + 128;                            // 64
    unsigned* xa    = fl0 + 192;                            // 128

    prep_kernel<<<dim3(256), dim3(256), 0, stream>>>(
        (unsigned short*)hs0, (unsigned short*)hs1, fl0);

    lstm_fused_kernel<<<dim3(512), dim3(256), 0, stream>>>(
        W_ih0, W_hh0, b_ih0, b_hh0, W_ih1, W_hh1, b_ih1, b_hh1,
        x, h0_all, hs0, hs1, hfin, fl0, fl1, flm, xa);

    fc_kernel<<<dim3(1), dim3(512), 0, stream>>>(hfin, W_fc, b_fc, (float*)d_out);
}

// Round 7
// 8519.728 us; speedup vs baseline: 594.5661x; 594.5661x over previous
//
#include <hip/hip_runtime.h>

// LSTMClassification: B=64, T=512, IN=128, H=512, 2 layers + FC(512->1)
// Round 7: flag-free data-polling. h exchange via step-indexed, canary-
// validated buffers: producers fire-and-forget 4B AGENT-scope atomic stores;
// consumers poll the 8B data words themselves (per-word predicated retry)
// until != canary (0xFF80 bf16 = -inf, unreachable since |h|<1).
// Removes the round-4 critical chain (publish-drain RT + flag store + flag
// poll RT) entirely -- detection IS data arrival.
//   L0 recurrence + L1 input: hrec0[t][wg][64][8] (33.5MB, canary-init by prep
//     each launch; each slot written once -- no reuse hazards).
//   L1 recurrence: hrec1 ring[8] with deferred self-re-canary: WG w restores
//     canary in its own 1KB of slot (t-4)&7 during step t. Safe by the
//     all-to-all argument: P validating h_t implies every Q passed step t-1
//     >= t-4 (canary restored+drained), and canary landed in MALL before
//     Q's h_{t-1} -- so P's later read of the slot sees canary-or-newer.
//     Per-step s_waitcnt vmcnt(0) before stores orders canary->data per WG.
// All cross-WG ops use __hip_atomic_* AGENT scope (the only grade proven
// coherent on this chip; round-6's sc0-only asm was falsified -- L1 served
// stale lines and every poll guard-broke: 512 * 2^17 * 75ns = the 5.1s).

#define NWG 64
#define NB 64
#define NT 512
#define NH 512
#define BLK 512                 // elements per WG block = 64 batches * 8 cols
#define SREC (NWG * BLK)        // elements per step slot = 32768 (64KB)
#define RING 8
#define CAN32 0xFF80FF80u

typedef float f32x4 __attribute__((ext_vector_type(4)));
typedef __bf16 bf16x4 __attribute__((ext_vector_type(4)));
typedef __bf16 bf16x8 __attribute__((ext_vector_type(8)));
typedef unsigned long long u64;
typedef unsigned u32;

__device__ __forceinline__ u64 lda8(const __bf16* p) {
    return __hip_atomic_load((const u64*)p, __ATOMIC_RELAXED, __HIP_MEMORY_SCOPE_AGENT);
}
__device__ __forceinline__ void sta4(u32* p, u32 v) {
    __hip_atomic_store(p, v, __ATOMIC_RELAXED, __HIP_MEMORY_SCOPE_AGENT);
}
__device__ __forceinline__ int valid8(u64 w) {
    return ((u32)w != CAN32) && ((u32)(w >> 32) != CAN32);
}
__device__ __forceinline__ unsigned short bfbits(float f) {
    __bf16 h = (__bf16)f; unsigned short u; __builtin_memcpy(&u, &h, 2); return u;
}

__global__ void prep_kernel(u64* hrec0, u64* hrec1, u64* hinit) {
    const u64 C = 0xFF80FF80FF80FF80ull;
    const size_t stride = (size_t)gridDim.x * blockDim.x;
    const size_t i = (size_t)blockIdx.x * blockDim.x + threadIdx.x;
    const size_t n0 = (size_t)NT * SREC / 4;        // 4,194,304 u64 (33.5MB)
    for (size_t k = i; k < n0; k += stride) hrec0[k] = C;
    if (i < (size_t)RING * SREC / 4) hrec1[i] = C;  // 65,536 u64 (512KB)
    if (i < SREC / 4) hinit[i] = 0;                 // zero h_{-1}
}

// issue 2N 8B loads for one A-operand group; if doval, retry invalid words
// (per-word predicated -- steady-state retries touch only late words).
template<int N>
__device__ __forceinline__ void load_validate(const __bf16* hp, int aoff, int bsub,
                                              u64* w, bool doval) {
    #pragma unroll
    for (int kk = 0; kk < N; ++kk) {
        const __bf16* b = hp + (4 * kk + bsub) * BLK + aoff;
        w[2 * kk]     = lda8(b);
        w[2 * kk + 1] = lda8(b + 2 * BLK);
    }
    if (doval) {
        int g = 0;
        for (;;) {
            u32 bad = 0;
            #pragma unroll
            for (int k = 0; k < 2 * N; ++k) bad |= (valid8(w[k]) ? 0u : 1u) << k;
            if (!bad) break;
            if (++g > (1 << 20)) break;   // safety: never hard-hang
            #pragma unroll
            for (int kk = 0; kk < N; ++kk) {
                const __bf16* b = hp + (4 * kk + bsub) * BLK + aoff;
                if (bad & (1u << (2 * kk)))     w[2 * kk]     = lda8(b);
                if (bad & (1u << (2 * kk + 1))) w[2 * kk + 1] = lda8(b + 2 * BLK);
            }
        }
    }
}

template<int KIH, int IS_L0>
__device__ void layer_loop(
    char* Wl, float (*gbuf)[36], int wg,
    const float* __restrict__ W_ih, const float* __restrict__ W_hh,
    const float* __restrict__ b_ih, const float* __restrict__ b_hh,
    const float* __restrict__ x_f32,     // L0 only: x [NB][NT][KIH] fp32 (cached)
    const __bf16* __restrict__ hrec0,    // [NT][NWG][NB][8] step-indexed (L0 out / L1 in)
    __bf16* __restrict__ hrec1,          // [RING][NWG][NB][8] (L1 recurrence ring)
    const __bf16* __restrict__ hinit,    // zero block [NWG][NB][8]
    float* __restrict__ hfin)            // L1 only: [NB][NH] fp32
{
    constexpr int KTOT = KIH + NH;
    constexpr int NCH_A = KIH / 32;
    constexpr int NCH_B = NH / 32;       // 16
    constexpr int ROWB = KTOT * 2;

    const int tid = threadIdx.x, lane = tid & 63, wid = tid >> 6;
    const int hcol0 = wg * 8;

    // ---- stage weight slice into LDS (bf16, row-XOR swizzle) ----
    {
        constexpr int CPR = KTOT / 8;
        for (int cid = tid; cid < 32 * CPR; cid += 256) {
            const int r = cid / CPR;
            const int k0 = (cid - r * CPR) * 8;
            const int grow = (r >> 3) * NH + hcol0 + (r & 7);
            const float* src = (k0 < KIH) ? (W_ih + (size_t)grow * KIH + k0)
                                          : (W_hh + (size_t)grow * NH + (k0 - KIH));
            union { __bf16 h[8]; uint4 u; } tmp;
            #pragma unroll
            for (int j = 0; j < 8; ++j) tmp.h[j] = (__bf16)src[j];
            const unsigned off = (unsigned)(r * ROWB) +
                (((unsigned)(2 * k0)) ^ ((unsigned)((r & 7) << 4)));
            *(uint4*)(Wl + off) = tmp.u;
        }
    }

    // epilogue mapping: thread -> (batch eb, cols ecp..ecp+1); biases folded
    const int eb = tid >> 2, ecp = (tid & 3) * 2;
    float bI[2], bF[2], bG[2], bO[2];
    #pragma unroll
    for (int j = 0; j < 2; ++j) {
        const int c = hcol0 + ecp + j;
        bI[j] = b_ih[c] + b_hh[c];
        bF[j] = b_ih[NH + c] + b_hh[NH + c];
        bG[j] = b_ih[2 * NH + c] + b_hh[2 * NH + c];
        bO[j] = b_ih[3 * NH + c] + b_hh[3 * NH + c];
    }
    float c0 = 0.f, c1 = 0.f;            // cell state in registers
    __syncthreads();

    // MFMA mapping: 4 waves = 4 batch-tiles; each wave does both gate-tiles
    const int bt = wid * 16;
    const int arow = bt + (lane & 15);
    const int q4 = ((lane >> 4) & 3) * 4;
    const char* wrow0 = Wl + (lane & 15) * ROWB;          // gate rows 0..15
    const char* wrow1 = wrow0 + 16 * ROWB;                // gate rows 16..31
    const unsigned bsz = (unsigned)((lane & 7) << 4);
    const int aoff = arow * 8 + (q4 & 4);
    const int bsub = (q4 >> 3);

    auto wfragp = [&](const char* wr, int k0) -> bf16x8 {
        const bf16x4 lo = *(const bf16x4*)(wr + (((unsigned)(2 * (k0 + q4))) ^ bsz));
        const bf16x4 hi = *(const bf16x4*)(wr + (((unsigned)(2 * (k0 + 16 + q4))) ^ bsz));
        return __builtin_shufflevector(lo, hi, 0, 1, 2, 3, 4, 5, 6, 7);
    };
    auto mk8 = [&](u64 a, u64 b) -> bf16x8 {
        bf16x4 lo, hi; __builtin_memcpy(&lo, &a, 8); __builtin_memcpy(&hi, &b, 8);
        return __builtin_shufflevector(lo, hi, 0, 1, 2, 3, 4, 5, 6, 7);
    };

    for (int t = 0; t < NT; ++t) {
        const __bf16* hprev;             // own-layer h_{t-1}
        __bf16* hout;                    // own-layer h_t destination
        if constexpr (IS_L0) {
            hprev = (t == 0) ? hinit : (hrec0 + (size_t)(t - 1) * SREC);
            hout = (__bf16*)hrec0 + (size_t)t * SREC;
        } else {
            hprev = (t == 0) ? hinit : (hrec1 + (size_t)((t - 1) & (RING - 1)) * SREC);
            hout = hrec1 + (size_t)(t & (RING - 1)) * SREC;
        }

        f32x4 a0c0 = {0,0,0,0}, a0c1 = {0,0,0,0};
        f32x4 a1c0 = {0,0,0,0}, a1c1 = {0,0,0,0};

        // issue recurrence loads first (they fly while we do phase A)
        u64 rb[2 * NCH_B];
        #pragma unroll
        for (int kk = 0; kk < NCH_B; ++kk) {
            const __bf16* b = hprev + (4 * kk + bsub) * BLK + aoff;
            rb[2 * kk]     = lda8(b);
            rb[2 * kk + 1] = lda8(b + 2 * BLK);
        }

        if constexpr (IS_L0) {
            // phase A from x (cached, independent)
            const float* xb = x_f32 + ((size_t)arow * NT + t) * KIH;
            #pragma unroll
            for (int kk = 0; kk < NCH_A; ++kk) {
                const float4 lo = *(const float4*)(xb + kk * 32 + q4);
                const float4 hi = *(const float4*)(xb + kk * 32 + 16 + q4);
                const bf16x4 alo = {(__bf16)lo.x, (__bf16)lo.y, (__bf16)lo.z, (__bf16)lo.w};
                const bf16x4 ahi = {(__bf16)hi.x, (__bf16)hi.y, (__bf16)hi.z, (__bf16)hi.w};
                const bf16x8 av = __builtin_shufflevector(alo, ahi, 0, 1, 2, 3, 4, 5, 6, 7);
                f32x4& d0 = (kk & 1) ? a0c1 : a0c0;
                d0 = __builtin_amdgcn_mfma_f32_16x16x32_bf16(av, wfragp(wrow0, kk * 32), d0, 0, 0, 0);
                f32x4& d1 = (kk & 1) ? a1c1 : a1c0;
                d1 = __builtin_amdgcn_mfma_f32_16x16x32_bf16(av, wfragp(wrow1, kk * 32), d1, 0, 0, 0);
            }
            // validate recurrence words (skip t=0: hinit is plain zeros)
            load_validate<NCH_B>(hprev, aoff, bsub, rb, t > 0);
        } else {
            // L1: issue phase-A loads (hrec0[t], produced by L0) to overlap
            u64 ra[2 * NCH_A];
            const __bf16* hA = hrec0 + (size_t)t * SREC;
            #pragma unroll
            for (int kk = 0; kk < NCH_A; ++kk) {
                const __bf16* b = hA + (4 * kk + bsub) * BLK + aoff;
                ra[2 * kk]     = lda8(b);
                ra[2 * kk + 1] = lda8(b + 2 * BLK);
            }
            // validate + MFMA recurrence first (own-layer data arrives early)
            load_validate<NCH_B>(hprev, aoff, bsub, rb, t > 0);
            #pragma unroll
            for (int kk = 0; kk < NCH_B; ++kk) {
                const bf16x8 av = mk8(rb[2 * kk], rb[2 * kk + 1]);
                f32x4& d0 = (kk & 1) ? a0c1 : a0c0;
                d0 = __builtin_amdgcn_mfma_f32_16x16x32_bf16(av, wfragp(wrow0, KIH + kk * 32), d0, 0, 0, 0);
                f32x4& d1 = (kk & 1) ? a1c1 : a1c0;
                d1 = __builtin_amdgcn_mfma_f32_16x16x32_bf16(av, wfragp(wrow1, KIH + kk * 32), d1, 0, 0, 0);
            }
            // validate + MFMA phase A (the just-in-time L0 arrival)
            load_validate<NCH_A>(hA, aoff, bsub, ra, true);
            #pragma unroll
            for (int kk = 0; kk < NCH_A; ++kk) {
                const bf16x8 av = mk8(ra[2 * kk], ra[2 * kk + 1]);
                f32x4& d0 = (kk & 1) ? a0c1 : a0c0;
                d0 = __builtin_amdgcn_mfma_f32_16x16x32_bf16(av, wfragp(wrow0, kk * 32), d0, 0, 0, 0);
                f32x4& d1 = (kk & 1) ? a1c1 : a1c0;
                d1 = __builtin_amdgcn_mfma_f32_16x16x32_bf16(av, wfragp(wrow1, kk * 32), d1, 0, 0, 0);
            }
        }

        if constexpr (IS_L0) {
            // recurrence MFMA (L0)
            #pragma unroll
            for (int kk = 0; kk < NCH_B; ++kk) {
                const bf16x8 av = mk8(rb[2 * kk], rb[2 * kk + 1]);
                f32x4& d0 = (kk & 1) ? a0c1 : a0c0;
                d0 = __builtin_amdgcn_mfma_f32_16x16x32_bf16(av, wfragp(wrow0, KIH + kk * 32), d0, 0, 0, 0);
                f32x4& d1 = (kk & 1) ? a1c1 : a1c0;
                d1 = __builtin_amdgcn_mfma_f32_16x16x32_bf16(av, wfragp(wrow1, KIH + kk * 32), d1, 0, 0, 0);
            }
        }

        const f32x4 s0 = a0c0 + a0c1, s1 = a1c0 + a1c1;
        #pragma unroll
        for (int i = 0; i < 4; ++i) {
            gbuf[bt + ((lane >> 4) & 3) * 4 + i][lane & 15]        = s0[i];
            gbuf[bt + ((lane >> 4) & 3) * 4 + i][16 + (lane & 15)] = s1[i];
        }
        __syncthreads();   // gbuf ready

        // order own canary->data stores (same address, 4 steps apart); in
        // steady state prior-step stores are long acked -> free.
        asm volatile("s_waitcnt vmcnt(0)" ::: "memory");

        // LSTM cell, fp32, 2 columns per thread; fire-and-forget publish
        {
            float hh[2]; float cc[2] = {c0, c1};
            #pragma unroll
            for (int j = 0; j < 2; ++j) {
                const int c = ecp + j;
                const float gi = gbuf[eb][c]      + bI[j];
                const float gf = gbuf[eb][8 + c]  + bF[j];
                const float gg = gbuf[eb][16 + c] + bG[j];
                const float go = gbuf[eb][24 + c] + bO[j];
                const float ii = 1.f / (1.f + __expf(-gi));
                const float ff = 1.f / (1.f + __expf(-gf));
                const float g2 = 2.f / (1.f + __expf(-2.f * gg)) - 1.f;
                const float oo = 1.f / (1.f + __expf(-go));
                const float cn = ff * cc[j] + ii * g2;
                const float th = 2.f / (1.f + __expf(-2.f * cn)) - 1.f;
                hh[j] = oo * th;
                cc[j] = cn;
            }
            c0 = cc[0]; c1 = cc[1];
            const u32 pk = (u32)bfbits(hh[0]) | ((u32)bfbits(hh[1]) << 16);
            sta4((u32*)(hout + (size_t)wg * BLK) + tid, pk);
            if constexpr (!IS_L0) {
                if (t >= 4)   // deferred re-canary of own 1KB in slot (t-4)&7
                    sta4((u32*)(hrec1 + (size_t)((t - 4) & (RING - 1)) * SREC
                                + (size_t)wg * BLK) + tid, CAN32);
                if (t == NT - 1) {
                    hfin[(size_t)eb * NH + hcol0 + ecp]     = hh[0];
                    hfin[(size_t)eb * NH + hcol0 + ecp + 1] = hh[1];
                }
            }
        }
        __syncthreads();   // protect gbuf for next step's scatter
    }
}

__launch_bounds__(256, 2)
__global__ void lstm_fused_kernel(
    const float* W_ih0, const float* W_hh0, const float* b_ih0, const float* b_hh0,
    const float* W_ih1, const float* W_hh1, const float* b_ih1, const float* b_hh1,
    const float* x, __bf16* hrec0, __bf16* hrec1, __bf16* hinit, float* hfin)
{
    __shared__ __align__(16) char Wl[32 * 2048];   // 64KB (L0 uses 40KB of it)
    __shared__ float gbuf[64][36];

    if (blockIdx.x < NWG) {
        layer_loop<128, 1>(Wl, gbuf, blockIdx.x,
                           W_ih0, W_hh0, b_ih0, b_hh0,
                           x, hrec0, nullptr, hinit, nullptr);
    } else {
        layer_loop<512, 0>(Wl, gbuf, blockIdx.x - NWG,
                           W_ih1, W_hh1, b_ih1, b_hh1,
                           nullptr, hrec0, hrec1, hinit, hfin);
    }
}

__global__ void fc_kernel(const float* __restrict__ hfin,
                          const float* __restrict__ w_fc,
                          const float* __restrict__ b_fc,
                          float* __restrict__ out) {
    __shared__ float red[64][9];
    const int tid = threadIdx.x;
    const int b = tid >> 3, p = tid & 7;
    const int k0 = p * 64;
    float s = 0.f;
    #pragma unroll 8
    for (int k = 0; k < 64; ++k) s += hfin[(size_t)b * NH + k0 + k] * w_fc[k0 + k];
    red[b][p] = s;
    __syncthreads();
    if (p == 0) {
        float a = 0.f;
        #pragma unroll
        for (int j = 0; j < 8; ++j) a += red[b][j];
        out[b] = a + b_fc[0];
    }
}

extern "C" void kernel_launch(void* const* d_in, const int* in_sizes, int n_in,
                              void* d_out, int out_size, void* d_ws, size_t ws_size,
                              hipStream_t stream) {
    const float* x     = (const float*)d_in[0];
    const float* W_ih0 = (const float*)d_in[1];
    const float* W_hh0 = (const float*)d_in[2];
    const float* b_ih0 = (const float*)d_in[3];
    const float* b_hh0 = (const float*)d_in[4];
    const float* W_ih1 = (const float*)d_in[5];
    const float* W_hh1 = (const float*)d_in[6];
    const float* b_ih1 = (const float*)d_in[7];
    const float* b_hh1 = (const float*)d_in[8];
    const float* W_fc  = (const float*)d_in[9];
    const float* b_fc  = (const float*)d_in[10];

    // workspace layout (bytes); total ~34.3 MB (same budget as rounds 1-6)
    char* ws = (char*)d_ws;
    __bf16* hrec0 = (__bf16*)(ws);                        // 512*32768*2 = 33,554,432
    __bf16* hrec1 = (__bf16*)(ws + 33554432);             // 8*32768*2   = 524,288
    __bf16* hinit = (__bf16*)(ws + 33554432 + 524288);    // 32768*2     = 65,536
    float*  hfin  = (float*) (ws + 33554432 + 589824);    // 64*512*4    = 131,072

    prep_kernel<<<dim3(2048), dim3(256), 0, stream>>>(
        (u64*)hrec0, (u64*)hrec1, (u64*)hinit);

    lstm_fused_kernel<<<dim3(2 * NWG), dim3(256), 0, stream>>>(
        W_ih0, W_hh0, b_ih0, b_hh0, W_ih1, W_hh1, b_ih1, b_hh1,
        x, hrec0, hrec1, hinit, hfin);

    fc_kernel<<<dim3(1), dim3(512), 0, stream>>>(hfin, W_fc, b_fc, (float*)d_out);
}

// Round 8
// 3888.438 us; speedup vs baseline: 1302.7189x; 2.1910x over previous
//
#include <hip/hip_runtime.h>

// LSTMClassification: B=64, T=512, IN=128, H=512, 2 layers + FC(512->1)
// Round 8 = round-4 champion body (3117us) with ONE targeted sync change:
// DENSE flag arrays (64 contiguous u32 per layer). Poll = 64 lanes x 4B in a
// 256B span = 4 MALL transactions/iteration (round-4's 64B-strided flags cost
// 64 transactions/iteration x ~192 polling waves = the MALL congestion that
// inflated every critical-path round trip). Publishers are plain relaxed
// AGENT-scope stores -- NO RMW (round-5 isolated RMW serialization as a
// regression). Secondary (round-5-validated): L0 publishes only h0_all[t] and
// reads its recurrence from h0_all[t-1] (halves L0 publish drain); cell state
// in registers. Everything else byte-equivalent to round 4: 512 threads,
// 8 waves = 4 batch-tiles x 2 gate-tiles, weights in LDS XOR-swizzled,
// WG-block-major h exchange, __hip_atomic_* AGENT scope only (the sole
// cross-WG grade proven coherent on this chip; round-6 sc0 asm falsified).

#define NWG 64
#define NB 64
#define NT 512
#define NH 512
#define BLK 512                 // elements per WG h-block (64 batches x 8 cols)
#define SREC (NWG * BLK)        // elements per step slot = 32768

typedef float f32x4 __attribute__((ext_vector_type(4)));
typedef __bf16 bf16x4 __attribute__((ext_vector_type(4)));
typedef __bf16 bf16x8 __attribute__((ext_vector_type(8)));
typedef unsigned long long u64;
typedef unsigned u32;

__device__ __forceinline__ bf16x4 ld8_bypass(const __bf16* p) {
    u64 v = __hip_atomic_load((const u64*)p, __ATOMIC_RELAXED, __HIP_MEMORY_SCOPE_AGENT);
    bf16x4 r; __builtin_memcpy(&r, &v, 8); return r;
}
__device__ __forceinline__ void st8_bypass(__bf16* p, u64 v) {
    __hip_atomic_store((u64*)p, v, __ATOMIC_RELAXED, __HIP_MEMORY_SCOPE_AGENT);
}

// One wave polls 64 DENSE flags (lane l watches flags[l]; 256B span = 4
// transactions per iteration) until all >= target.
__device__ __forceinline__ void wait_flags(const unsigned* flags, unsigned target, int lane) {
    int g = 0;
    for (;;) {
        unsigned f = __hip_atomic_load((unsigned*)&flags[lane],
                                       __ATOMIC_RELAXED, __HIP_MEMORY_SCOPE_AGENT);
        if (__all((int)(f >= target))) break;
        if (++g > (1 << 17)) break;    // safety: never hard-hang
    }
}

__device__ __forceinline__ unsigned short bfbits(float f) {
    __bf16 h = (__bf16)f; unsigned short u; __builtin_memcpy(&u, &h, 2); return u;
}

__global__ void prep_kernel(unsigned short* hinit, unsigned short* hs1, unsigned* fl) {
    int i = blockIdx.x * blockDim.x + threadIdx.x;
    if (i < SREC) hinit[i] = 0;                    // zero h_{-1} block
    if (i < 2 * SREC) hs1[i] = 0;                  // L1 parity buffers
    if (i < 128) fl[i] = 0;                        // fl0[64] ++ fl1[64] (dense)
}

template<int KIH, int IS_L0>
__device__ __forceinline__ void layer_body(
    char* Wl, float (*gbuf)[36], unsigned short (*hstage)[8],
    int wg,
    const float* __restrict__ W_ih, const float* __restrict__ W_hh,
    const float* __restrict__ b_ih, const float* __restrict__ b_hh,
    const float* __restrict__ x_f32,       // L0: x [NB][NT][KIH] fp32 (cached)
    __bf16* __restrict__ h0_all,           // [NT][NWG][BLK] step-indexed (L0 out / both read)
    const __bf16* __restrict__ hinit,      // zero block [NWG][BLK]
    __bf16* __restrict__ hbuf,             // L1: [2][NWG][BLK] parity buffer
    float* __restrict__ h_final,           // L1: [NB][NH] fp32
    unsigned* __restrict__ flags_self,     // [64] dense, this layer
    const unsigned* __restrict__ flags_dep)// [64] dense, producer layer (L1)
{
    constexpr int KTOT = KIH + NH;
    constexpr int NCH_A = KIH / 32;
    constexpr int NCH_B = NH / 32;         // 16
    constexpr int ROWB = KTOT * 2;

    const int tid = threadIdx.x;
    const int hcol0 = wg * 8;

    // ---- stage weight slice into LDS (bf16, row-XOR swizzle) ----
    {
        constexpr int CPR = KTOT / 8;
        for (int cid = tid; cid < 32 * CPR; cid += 512) {
            const int r = cid / CPR;
            const int k0 = (cid - r * CPR) * 8;
            const int grow = (r >> 3) * NH + hcol0 + (r & 7);
            const float* src = (k0 < KIH) ? (W_ih + (size_t)grow * KIH + k0)
                                          : (W_hh + (size_t)grow * NH + (k0 - KIH));
            union { __bf16 h[8]; uint4 u; } tmp;
            #pragma unroll
            for (int j = 0; j < 8; ++j) tmp.h[j] = (__bf16)src[j];
            const unsigned off = (unsigned)(r * ROWB) +
                (((unsigned)(2 * k0)) ^ ((unsigned)((r & 7) << 4)));
            *(uint4*)(Wl + off) = tmp.u;
        }
    }

    // epilogue mapping + folded biases; cell state in registers
    const int eb = tid >> 3, ec = tid & 7;
    const int hcE = hcol0 + ec;
    const float bI = b_ih[hcE]          + b_hh[hcE];
    const float bF = b_ih[NH + hcE]     + b_hh[NH + hcE];
    const float bG = b_ih[2 * NH + hcE] + b_hh[2 * NH + hcE];
    const float bO = b_ih[3 * NH + hcE] + b_hh[3 * NH + hcE];
    float creg = 0.0f;
    __syncthreads();

    // MFMA mapping: 8 waves = 4 batch-tiles x 2 gate-tiles of 16x16
    const int lane = tid & 63;
    const int wid = tid >> 6;
    const int bt = (wid & 3) * 16;
    const int gt = (wid >> 2) * 16;
    const int arow = bt + (lane & 15);
    const int q4 = ((lane >> 4) & 3) * 4;
    const int brow = gt + (lane & 15);
    const char* wrow = Wl + brow * ROWB;
    const unsigned bsz = (unsigned)((brow & 7) << 4);

    // block-layout A-fragment offsets
    const int aoff = arow * 8 + (q4 & 4);
    const int bsub = (q4 >> 3);

    auto wfrag = [&](int k0) -> bf16x8 {
        const bf16x4 blo = *(const bf16x4*)(wrow + (((unsigned)(2 * (k0 + q4))) ^ bsz));
        const bf16x4 bhi = *(const bf16x4*)(wrow + (((unsigned)(2 * (k0 + 16 + q4))) ^ bsz));
        return __builtin_shufflevector(blo, bhi, 0, 1, 2, 3, 4, 5, 6, 7);
    };

    for (int t = 0; t < NT; ++t) {
        const __bf16* __restrict__ hprev;
        __bf16* __restrict__ hout;
        if constexpr (IS_L0 != 0) {
            hprev = (t == 0) ? hinit : (h0_all + (size_t)(t - 1) * SREC);
            hout = h0_all + (size_t)t * SREC;
        } else {
            hprev = hbuf + (size_t)(t & 1) * SREC;
            hout = hbuf + (size_t)((t + 1) & 1) * SREC;
        }

        f32x4 accA0 = {0.f,0.f,0.f,0.f}, accA1 = {0.f,0.f,0.f,0.f};
        f32x4 accB0 = {0.f,0.f,0.f,0.f}, accB1 = {0.f,0.f,0.f,0.f};

        if constexpr (IS_L0 != 0) {
            // phase A from x (cached, independent of recurrence) BEFORE the wait
            const float* xb = x_f32 + ((size_t)arow * NT + t) * KIH;
            bf16x8 av[NCH_A];
            #pragma unroll
            for (int kk = 0; kk < NCH_A; ++kk) {
                const float4 lo = *(const float4*)(xb + kk * 32 + q4);
                const float4 hi = *(const float4*)(xb + kk * 32 + 16 + q4);
                const bf16x4 alo = {(__bf16)lo.x, (__bf16)lo.y, (__bf16)lo.z, (__bf16)lo.w};
                const bf16x4 ahi = {(__bf16)hi.x, (__bf16)hi.y, (__bf16)hi.z, (__bf16)hi.w};
                av[kk] = __builtin_shufflevector(alo, ahi, 0, 1, 2, 3, 4, 5, 6, 7);
            }
            #pragma unroll
            for (int kk = 0; kk < NCH_A; ++kk) {
                f32x4& a = (kk & 1) ? accA1 : accA0;
                a = __builtin_amdgcn_mfma_f32_16x16x32_bf16(av[kk], wfrag(kk * 32), a, 0, 0, 0);
            }
            if (t > 0 && wid == 0) wait_flags(flags_self, (unsigned)t, lane);
            __syncthreads();
        } else {
            // L1: wave0 waits for producer step t; wave1 for own recurrence t-1
            if (wid == 0) wait_flags(flags_dep, (unsigned)(t + 1), lane);
            if (wid == 1 && t > 0) wait_flags(flags_self, (unsigned)t, lane);
            __syncthreads();
        }

        // ---- preload A-fragments (block layout, coalesced bypass loads) ----
        bf16x4 aBlo[NCH_B], aBhi[NCH_B];
        #pragma unroll
        for (int kk = 0; kk < NCH_B; ++kk) {
            const __bf16* base = hprev + (4 * kk + bsub) * BLK + aoff;
            aBlo[kk] = ld8_bypass(base);
            aBhi[kk] = ld8_bypass(base + 2 * BLK);
        }
        if constexpr (IS_L0 == 0) {
            const __bf16* hA = h0_all + (size_t)t * SREC;
            bf16x4 aAlo[NCH_A], aAhi[NCH_A];
            #pragma unroll
            for (int kk = 0; kk < NCH_A; ++kk) {
                const __bf16* base = hA + (4 * kk + bsub) * BLK + aoff;
                aAlo[kk] = ld8_bypass(base);
                aAhi[kk] = ld8_bypass(base + 2 * BLK);
            }
            #pragma unroll
            for (int kk = 0; kk < NCH_A; ++kk) {
                f32x4& a = (kk & 1) ? accA1 : accA0;
                const bf16x8 av = __builtin_shufflevector(aAlo[kk], aAhi[kk], 0,1,2,3,4,5,6,7);
                a = __builtin_amdgcn_mfma_f32_16x16x32_bf16(av, wfrag(kk * 32), a, 0, 0, 0);
            }
        }
        #pragma unroll
        for (int kk = 0; kk < NCH_B; ++kk) {
            f32x4& a = (kk & 1) ? accB1 : accB0;
            const bf16x8 av = __builtin_shufflevector(aBlo[kk], aBhi[kk], 0,1,2,3,4,5,6,7);
            a = __builtin_amdgcn_mfma_f32_16x16x32_bf16(av, wfrag(KIH + kk * 32), a, 0, 0, 0);
        }

        const f32x4 acc = (accA0 + accA1) + (accB0 + accB1);

        // scatter C tile (row = batch = (lane>>4)*4+i, col = gate = lane&15)
        #pragma unroll
        for (int i = 0; i < 4; ++i)
            gbuf[bt + ((lane >> 4) & 3) * 4 + i][gt + (lane & 15)] = acc[i];
        __syncthreads();

        // LSTM cell, fp32 (gate order i, f, g, o); cell state in register
        {
            const float gi = gbuf[eb][ec]      + bI;
            const float gf = gbuf[eb][8 + ec]  + bF;
            const float gg = gbuf[eb][16 + ec] + bG;
            const float go = gbuf[eb][24 + ec] + bO;
            const float ii = 1.0f / (1.0f + __expf(-gi));
            const float ff = 1.0f / (1.0f + __expf(-gf));
            const float g2 = 2.0f / (1.0f + __expf(-2.0f * gg)) - 1.0f;   // tanh
            const float oo = 1.0f / (1.0f + __expf(-go));
            const float cn = ff * creg + ii * g2;
            const float th = 2.0f / (1.0f + __expf(-2.0f * cn)) - 1.0f;
            const float hn = oo * th;
            creg = cn;
            hstage[eb][ec] = bfbits(hn);
            if constexpr (IS_L0 == 0) {
                if (t == NT - 1) h_final[(size_t)eb * NH + hcol0 + ec] = hn;
            }
        }
        __syncthreads();

        // publish this WG's contiguous 1KB block: 128 threads x 8B bypass stores
        if (tid < 128) {
            u64 v;
            __builtin_memcpy(&v, &hstage[tid >> 1][(tid & 1) * 4], 8);
            st8_bypass(hout + (size_t)wg * BLK + tid * 4, v);
        }
        asm volatile("s_waitcnt vmcnt(0)" ::: "memory");   // drain own stores
        __syncthreads();                                   // all waves drained
        if (tid == 0)
            __hip_atomic_store(&flags_self[wg], (unsigned)(t + 1),
                               __ATOMIC_RELAXED, __HIP_MEMORY_SCOPE_AGENT);
    }
}

__launch_bounds__(512, 2)
__global__ void lstm_fused_kernel(
    const float* W_ih0, const float* W_hh0, const float* b_ih0, const float* b_hh0,
    const float* W_ih1, const float* W_hh1, const float* b_ih1, const float* b_hh1,
    const float* x, __bf16* h0_all, __bf16* hinit, __bf16* hs1,
    float* hfin, unsigned* fl0, unsigned* fl1)
{
    __shared__ __align__(16) char Wl[32 * 2048];    // 64KB (L0 uses 40KB)
    __shared__ float gbuf[64][36];
    __shared__ unsigned short hstage[64][8];

    if (blockIdx.x < NWG) {
        layer_body<128, 1>(Wl, gbuf, hstage, blockIdx.x,
                           W_ih0, W_hh0, b_ih0, b_hh0,
                           x, h0_all, hinit, nullptr, nullptr, fl0, nullptr);
    } else {
        layer_body<512, 0>(Wl, gbuf, hstage, blockIdx.x - NWG,
                           W_ih1, W_hh1, b_ih1, b_hh1,
                           nullptr, h0_all, hinit, hs1, hfin, fl1, fl0);
    }
}

__global__ void fc_kernel(const float* __restrict__ hfin,
                          const float* __restrict__ w_fc,
                          const float* __restrict__ b_fc,
                          float* __restrict__ out) {
    __shared__ float red[64][9];
    const int tid = threadIdx.x;
    const int b = tid >> 3, p = tid & 7;
    const int k0 = p * 64;
    float s = 0.f;
    #pragma unroll 8
    for (int k = 0; k < 64; ++k) s += hfin[(size_t)b * NH + k0 + k] * w_fc[k0 + k];
    red[b][p] = s;
    __syncthreads();
    if (p == 0) {
        float a = 0.f;
        #pragma unroll
        for (int j = 0; j < 8; ++j) a += red[b][j];
        out[b] = a + b_fc[0];
    }
}

extern "C" void kernel_launch(void* const* d_in, const int* in_sizes, int n_in,
                              void* d_out, int out_size, void* d_ws, size_t ws_size,
                              hipStream_t stream) {
    const float* x     = (const float*)d_in[0];
    const float* W_ih0 = (const float*)d_in[1];
    const float* W_hh0 = (const float*)d_in[2];
    const float* b_ih0 = (const float*)d_in[3];
    const float* b_hh0 = (const float*)d_in[4];
    const float* W_ih1 = (const float*)d_in[5];
    const float* W_hh1 = (const float*)d_in[6];
    const float* b_ih1 = (const float*)d_in[7];
    const float* b_hh1 = (const float*)d_in[8];
    const float* W_fc  = (const float*)d_in[9];
    const float* b_fc  = (const float*)d_in[10];

    // workspace layout (bytes); total ~33.95 MB
    char* ws = (char*)d_ws;
    __bf16*  h0_all = (__bf16*)(ws);                        // 512*32768*2 = 33,554,432
    __bf16*  hinit  = (__bf16*)(ws + 33554432);             // 32768*2 = 65,536
    __bf16*  hs1    = (__bf16*)(ws + 33554432 + 65536);     // 2*32768*2 = 131,072
    float*   hfin   = (float*) (ws + 33554432 + 196608);    // 64*512*4 = 131,072
    unsigned* fl0   = (unsigned*)(ws + 33554432 + 327680);  // 64 u32 dense
    unsigned* fl1   = fl0 + 64;                             // 64 u32 dense

    prep_kernel<<<dim3(256), dim3(256), 0, stream>>>(
        (unsigned short*)hinit, (unsigned short*)hs1, fl0);

    lstm_fused_kernel<<<dim3(2 * NWG), dim3(512), 0, stream>>>(
        W_ih0, W_hh0, b_ih0, b_hh0, W_ih1, W_hh1, b_ih1, b_hh1,
        x, h0_all, hinit, hs1, hfin, fl0, fl1);

    fc_kernel<<<dim3(1), dim3(512), 0, stream>>>(hfin, W_fc, b_fc, (float*)d_out);
}

// Round 9
// 3123.217 us; speedup vs baseline: 1621.8986x; 1.2450x over previous
//
#include <hip/hip_runtime.h>

// LSTMClassification: B=64, T=512, IN=128, H=512, 2 layers + FC(512->1)
// Round 9 = round-4 champion sync (padded per-WG flags, plain relaxed stores,
// AGENT-scope intrinsics only) + ONE structural change: 4-wave mapping
// (256 threads; each wave computes BOTH gate-tiles) so every A-fragment is
// bypass-loaded ONCE per WG instead of twice. Uncached MALL volume/step:
// 24MB -> 12.1MB. Theory: rounds 4-8 sat at the uncached-exchange bandwidth
// ceiling (~4 TB/s effective), explaining why flag-layout tweaks bounced off
// it (R5 packed+RMW and R8 dense both REGRESSED -> packed flag lines create
// producer store contention; padded flags are optimal).
// L0 publishes step-indexed h0_all[t] only; L1 keeps a parity buffer.
// __launch_bounds__(256,2): 256-VGPR budget keeps L1's 64 8B loads in flight.

#define NWG 64
#define NB 64
#define NT 512
#define NH 512
#define BLK 512                 // elements per WG h-block (64 batches x 8 cols)
#define SREC (NWG * BLK)        // elements per step slot = 32768
#define FPAD 16                 // flag padding (u32) = 64B exclusive line/WG

typedef float f32x4 __attribute__((ext_vector_type(4)));
typedef __bf16 bf16x4 __attribute__((ext_vector_type(4)));
typedef __bf16 bf16x8 __attribute__((ext_vector_type(8)));
typedef unsigned long long u64;
typedef unsigned u32;

__device__ __forceinline__ bf16x4 ld8_bypass(const __bf16* p) {
    u64 v = __hip_atomic_load((const u64*)p, __ATOMIC_RELAXED, __HIP_MEMORY_SCOPE_AGENT);
    bf16x4 r; __builtin_memcpy(&r, &v, 8); return r;
}
__device__ __forceinline__ void st8_bypass(__bf16* p, u64 v) {
    __hip_atomic_store((u64*)p, v, __ATOMIC_RELAXED, __HIP_MEMORY_SCOPE_AGENT);
}

// One wave polls 64 padded flags (lane l watches flags[l*FPAD]) until all >= target.
__device__ __forceinline__ void wait_flags(const unsigned* flags, unsigned target, int lane) {
    int g = 0;
    for (;;) {
        unsigned f = __hip_atomic_load((unsigned*)&flags[lane * FPAD],
                                       __ATOMIC_RELAXED, __HIP_MEMORY_SCOPE_AGENT);
        if (__all((int)(f >= target))) break;
        if (++g > (1 << 17)) break;    // safety: never hard-hang
    }
}

__device__ __forceinline__ unsigned short bfbits(float f) {
    __bf16 h = (__bf16)f; unsigned short u; __builtin_memcpy(&u, &h, 2); return u;
}

__global__ void prep_kernel(unsigned short* hinit, unsigned short* hs1, unsigned* fl) {
    int i = blockIdx.x * blockDim.x + threadIdx.x;
    if (i < SREC) hinit[i] = 0;                    // zero h_{-1} block
    if (i < 2 * SREC) hs1[i] = 0;                  // L1 parity buffers
    if (i < 2 * NWG * FPAD) fl[i] = 0;             // padded flags, both layers
}

template<int KIH, int IS_L0>
__device__ __forceinline__ void layer_body(
    char* Wl, float (*gbuf)[36], u32 (*hstage32)[4],
    int wg,
    const float* __restrict__ W_ih, const float* __restrict__ W_hh,
    const float* __restrict__ b_ih, const float* __restrict__ b_hh,
    const float* __restrict__ x_f32,       // L0: x [NB][NT][KIH] fp32 (cached)
    __bf16* __restrict__ h0_all,           // [NT][NWG][BLK] step-indexed (L0 out / both read)
    const __bf16* __restrict__ hinit,      // zero block [NWG][BLK]
    __bf16* __restrict__ hbuf,             // L1: [2][NWG][BLK] parity buffer
    float* __restrict__ h_final,           // L1: [NB][NH] fp32
    unsigned* __restrict__ flags_self,     // [64*FPAD] this layer
    const unsigned* __restrict__ flags_dep)// [64*FPAD] producer layer (L1)
{
    constexpr int KTOT = KIH + NH;
    constexpr int NCH_A = KIH / 32;
    constexpr int NCH_B = NH / 32;         // 16
    constexpr int ROWB = KTOT * 2;

    const int tid = threadIdx.x;
    const int hcol0 = wg * 8;

    // ---- stage weight slice into LDS (bf16, row-XOR swizzle) ----
    {
        constexpr int CPR = KTOT / 8;
        for (int cid = tid; cid < 32 * CPR; cid += 256) {
            const int r = cid / CPR;
            const int k0 = (cid - r * CPR) * 8;
            const int grow = (r >> 3) * NH + hcol0 + (r & 7);
            const float* src = (k0 < KIH) ? (W_ih + (size_t)grow * KIH + k0)
                                          : (W_hh + (size_t)grow * NH + (k0 - KIH));
            union { __bf16 h[8]; uint4 u; } tmp;
            #pragma unroll
            for (int j = 0; j < 8; ++j) tmp.h[j] = (__bf16)src[j];
            const unsigned off = (unsigned)(r * ROWB) +
                (((unsigned)(2 * k0)) ^ ((unsigned)((r & 7) << 4)));
            *(uint4*)(Wl + off) = tmp.u;
        }
    }

    // epilogue mapping: thread -> (batch eb, cols ecp..ecp+1); cell in registers
    const int eb = tid >> 2, ecp = (tid & 3) * 2;
    float bI[2], bF[2], bG[2], bO[2];
    #pragma unroll
    for (int j = 0; j < 2; ++j) {
        const int c = hcol0 + ecp + j;
        bI[j] = b_ih[c] + b_hh[c];
        bF[j] = b_ih[NH + c] + b_hh[NH + c];
        bG[j] = b_ih[2 * NH + c] + b_hh[2 * NH + c];
        bO[j] = b_ih[3 * NH + c] + b_hh[3 * NH + c];
    }
    float c0 = 0.f, c1 = 0.f;
    __syncthreads();

    // MFMA mapping: 4 waves = 4 batch-tiles; each wave does BOTH gate-tiles
    const int lane = tid & 63;
    const int wid = tid >> 6;
    const int bt = wid * 16;
    const int arow = bt + (lane & 15);
    const int q4 = ((lane >> 4) & 3) * 4;
    const char* wrow0 = Wl + (lane & 15) * ROWB;          // gate rows 0..15
    const char* wrow1 = wrow0 + 16 * ROWB;                // gate rows 16..31
    const unsigned bsz = (unsigned)((lane & 7) << 4);
    const int aoff = arow * 8 + (q4 & 4);
    const int bsub = (q4 >> 3);

    auto wfragp = [&](const char* wr, int k0) -> bf16x8 {
        const bf16x4 lo = *(const bf16x4*)(wr + (((unsigned)(2 * (k0 + q4))) ^ bsz));
        const bf16x4 hi = *(const bf16x4*)(wr + (((unsigned)(2 * (k0 + 16 + q4))) ^ bsz));
        return __builtin_shufflevector(lo, hi, 0, 1, 2, 3, 4, 5, 6, 7);
    };
    auto mk8 = [&](bf16x4 lo, bf16x4 hi) -> bf16x8 {
        return __builtin_shufflevector(lo, hi, 0, 1, 2, 3, 4, 5, 6, 7);
    };

    for (int t = 0; t < NT; ++t) {
        const __bf16* __restrict__ hprev;
        __bf16* __restrict__ hout;
        if constexpr (IS_L0 != 0) {
            hprev = (t == 0) ? hinit : (h0_all + (size_t)(t - 1) * SREC);
            hout = h0_all + (size_t)t * SREC;
        } else {
            hprev = hbuf + (size_t)(t & 1) * SREC;
            hout = hbuf + (size_t)((t + 1) & 1) * SREC;
        }

        f32x4 p0a = {0,0,0,0}, p0b = {0,0,0,0};   // gate-tile 0, 2 chains
        f32x4 p1a = {0,0,0,0}, p1b = {0,0,0,0};   // gate-tile 1, 2 chains

        if constexpr (IS_L0 != 0) {
            // phase A from x (cached, independent of recurrence) BEFORE the wait
            const float* xb = x_f32 + ((size_t)arow * NT + t) * KIH;
            #pragma unroll
            for (int kk = 0; kk < NCH_A; ++kk) {
                const float4 lo = *(const float4*)(xb + kk * 32 + q4);
                const float4 hi = *(const float4*)(xb + kk * 32 + 16 + q4);
                const bf16x4 alo = {(__bf16)lo.x, (__bf16)lo.y, (__bf16)lo.z, (__bf16)lo.w};
                const bf16x4 ahi = {(__bf16)hi.x, (__bf16)hi.y, (__bf16)hi.z, (__bf16)hi.w};
                const bf16x8 av = mk8(alo, ahi);
                f32x4& d0 = (kk & 1) ? p0b : p0a;
                d0 = __builtin_amdgcn_mfma_f32_16x16x32_bf16(av, wfragp(wrow0, kk * 32), d0, 0, 0, 0);
                f32x4& d1 = (kk & 1) ? p1b : p1a;
                d1 = __builtin_amdgcn_mfma_f32_16x16x32_bf16(av, wfragp(wrow1, kk * 32), d1, 0, 0, 0);
            }
            if (t > 0 && wid == 0) wait_flags(flags_self, (unsigned)t, lane);
            __syncthreads();
        } else {
            // L1: wave0 waits for producer step t; wave1 for own recurrence t-1
            if (wid == 0) wait_flags(flags_dep, (unsigned)(t + 1), lane);
            if (wid == 1 && t > 0) wait_flags(flags_self, (unsigned)t, lane);
            __syncthreads();
        }

        // ---- preload A-fragments (block layout, coalesced bypass, loaded ONCE) ----
        bf16x4 aBlo[NCH_B], aBhi[NCH_B];
        #pragma unroll
        for (int kk = 0; kk < NCH_B; ++kk) {
            const __bf16* base = hprev + (4 * kk + bsub) * BLK + aoff;
            aBlo[kk] = ld8_bypass(base);
            aBhi[kk] = ld8_bypass(base + 2 * BLK);
        }
        if constexpr (IS_L0 == 0) {
            const __bf16* hA = h0_all + (size_t)t * SREC;
            bf16x4 aAlo[NCH_A], aAhi[NCH_A];
            #pragma unroll
            for (int kk = 0; kk < NCH_A; ++kk) {
                const __bf16* base = hA + (4 * kk + bsub) * BLK + aoff;
                aAlo[kk] = ld8_bypass(base);
                aAhi[kk] = ld8_bypass(base + 2 * BLK);
            }
            #pragma unroll
            for (int kk = 0; kk < NCH_A; ++kk) {
                const bf16x8 av = mk8(aAlo[kk], aAhi[kk]);
                f32x4& d0 = (kk & 1) ? p0b : p0a;
                d0 = __builtin_amdgcn_mfma_f32_16x16x32_bf16(av, wfragp(wrow0, kk * 32), d0, 0, 0, 0);
                f32x4& d1 = (kk & 1) ? p1b : p1a;
                d1 = __builtin_amdgcn_mfma_f32_16x16x32_bf16(av, wfragp(wrow1, kk * 32), d1, 0, 0, 0);
            }
        }
        #pragma unroll
        for (int kk = 0; kk < NCH_B; ++kk) {
            const bf16x8 av = mk8(aBlo[kk], aBhi[kk]);
            f32x4& d0 = (kk & 1) ? p0b : p0a;
            d0 = __builtin_amdgcn_mfma_f32_16x16x32_bf16(av, wfragp(wrow0, KIH + kk * 32), d0, 0, 0, 0);
            f32x4& d1 = (kk & 1) ? p1b : p1a;
            d1 = __builtin_amdgcn_mfma_f32_16x16x32_bf16(av, wfragp(wrow1, KIH + kk * 32), d1, 0, 0, 0);
        }

        const f32x4 s0 = p0a + p0b, s1 = p1a + p1b;
        #pragma unroll
        for (int i = 0; i < 4; ++i) {
            gbuf[bt + ((lane >> 4) & 3) * 4 + i][lane & 15]        = s0[i];
            gbuf[bt + ((lane >> 4) & 3) * 4 + i][16 + (lane & 15)] = s1[i];
        }
        __syncthreads();

        // LSTM cell, fp32, 2 columns per thread (gate order i, f, g, o)
        {
            float hh[2]; float cc[2] = {c0, c1};
            #pragma unroll
            for (int j = 0; j < 2; ++j) {
                const int c = ecp + j;
                const float gi = gbuf[eb][c]      + bI[j];
                const float gf = gbuf[eb][8 + c]  + bF[j];
                const float gg = gbuf[eb][16 + c] + bG[j];
                const float go = gbuf[eb][24 + c] + bO[j];
                const float ii = 1.f / (1.f + __expf(-gi));
                const float ff = 1.f / (1.f + __expf(-gf));
                const float g2 = 2.f / (1.f + __expf(-2.f * gg)) - 1.f;   // tanh
                const float oo = 1.f / (1.f + __expf(-go));
                const float cn = ff * cc[j] + ii * g2;
                const float th = 2.f / (1.f + __expf(-2.f * cn)) - 1.f;
                hh[j] = oo * th;
                cc[j] = cn;
            }
            c0 = cc[0]; c1 = cc[1];
            hstage32[eb][tid & 3] = (u32)bfbits(hh[0]) | ((u32)bfbits(hh[1]) << 16);
            if constexpr (IS_L0 == 0) {
                if (t == NT - 1) {
                    h_final[(size_t)eb * NH + hcol0 + ecp]     = hh[0];
                    h_final[(size_t)eb * NH + hcol0 + ecp + 1] = hh[1];
                }
            }
        }
        __syncthreads();

        // publish this WG's contiguous 1KB block: 128 threads x 8B bypass stores
        if (tid < 128) {
            const u64 v = ((const u64*)hstage32)[tid];
            st8_bypass(hout + (size_t)wg * BLK + tid * 4, v);
        }
        asm volatile("s_waitcnt vmcnt(0)" ::: "memory");   // drain own stores
        __syncthreads();                                   // all waves drained
        if (tid == 0)
            __hip_atomic_store(&flags_self[wg * FPAD], (unsigned)(t + 1),
                               __ATOMIC_RELAXED, __HIP_MEMORY_SCOPE_AGENT);
    }
}

__launch_bounds__(256, 2)
__global__ void lstm_fused_kernel(
    const float* W_ih0, const float* W_hh0, const float* b_ih0, const float* b_hh0,
    const float* W_ih1, const float* W_hh1, const float* b_ih1, const float* b_hh1,
    const float* x, __bf16* h0_all, __bf16* hinit, __bf16* hs1,
    float* hfin, unsigned* fl0, unsigned* fl1)
{
    __shared__ __align__(16) char Wl[32 * 2048];    // 64KB (L0 uses 40KB)
    __shared__ float gbuf[64][36];
    __shared__ u32 hstage32[64][4];

    if (blockIdx.x < NWG) {
        layer_body<128, 1>(Wl, gbuf, hstage32, blockIdx.x,
                           W_ih0, W_hh0, b_ih0, b_hh0,
                           x, h0_all, hinit, nullptr, nullptr, fl0, nullptr);
    } else {
        layer_body<512, 0>(Wl, gbuf, hstage32, blockIdx.x - NWG,
                           W_ih1, W_hh1, b_ih1, b_hh1,
                           nullptr, h0_all, hinit, hs1, hfin, fl1, fl0);
    }
}

__global__ void fc_kernel(const float* __restrict__ hfin,
                          const float* __restrict__ w_fc,
                          const float* __restrict__ b_fc,
                          float* __restrict__ out) {
    __shared__ float red[64][9];
    const int tid = threadIdx.x;
    const int b = tid >> 3, p = tid & 7;
    const int k0 = p * 64;
    float s = 0.f;
    #pragma unroll 8
    for (int k = 0; k < 64; ++k) s += hfin[(size_t)b * NH + k0 + k] * w_fc[k0 + k];
    red[b][p] = s;
    __syncthreads();
    if (p == 0) {
        float a = 0.f;
        #pragma unroll
        for (int j = 0; j < 8; ++j) a += red[b][j];
        out[b] = a + b_fc[0];
    }
}

extern "C" void kernel_launch(void* const* d_in, const int* in_sizes, int n_in,
                              void* d_out, int out_size, void* d_ws, size_t ws_size,
                              hipStream_t stream) {
    const float* x     = (const float*)d_in[0];
    const float* W_ih0 = (const float*)d_in[1];
    const float* W_hh0 = (const float*)d_in[2];
    const float* b_ih0 = (const float*)d_in[3];
    const float* b_hh0 = (const float*)d_in[4];
    const float* W_ih1 = (const float*)d_in[5];
    const float* W_hh1 = (const float*)d_in[6];
    const float* b_ih1 = (const float*)d_in[7];
    const float* b_hh1 = (const float*)d_in[8];
    const float* W_fc  = (const float*)d_in[9];
    const float* b_fc  = (const float*)d_in[10];

    // workspace layout (bytes); total ~33.96 MB
    char* ws = (char*)d_ws;
    __bf16*  h0_all = (__bf16*)(ws);                        // 512*32768*2 = 33,554,432
    __bf16*  hinit  = (__bf16*)(ws + 33554432);             // 32768*2 = 65,536
    __bf16*  hs1    = (__bf16*)(ws + 33554432 + 65536);     // 2*32768*2 = 131,072
    float*   hfin   = (float*) (ws + 33554432 + 196608);    // 64*512*4 = 131,072
    unsigned* fl0   = (unsigned*)(ws + 33554432 + 327680);  // 64*16 u32 = 4KB
    unsigned* fl1   = fl0 + NWG * FPAD;                     // 4KB

    prep_kernel<<<dim3(256), dim3(256), 0, stream>>>(
        (unsigned short*)hinit, (unsigned short*)hs1, fl0);

    lstm_fused_kernel<<<dim3(2 * NWG), dim3(256), 0, stream>>>(
        W_ih0, W_hh0, b_ih0, b_hh0, W_ih1, W_hh1, b_ih1, b_hh1,
        x, h0_all, hinit, hs1, hfin, fl0, fl1);

    fc_kernel<<<dim3(1), dim3(512), 0, stream>>>(hfin, W_fc, b_fc, (float*)d_out);
}